// Round 1
// baseline (1459.839 us; speedup 1.0000x reference)
//
#include <hip/hip_runtime.h>
#include <math.h>

// Problem constants (fixed by the reference setup_inputs()):
#define D_MODEL 1024
#define HEADS   16
#define HDIM    64      // D_MODEL / HEADS
#define CHUNK   128
#define B_SZ    4
#define L_SEQ   2048
#define NCHUNK  (L_SEQ / CHUNK)      // 16
#define NTOK    (B_SZ * L_SEQ)       // 8192
#define EPS_DEN 1e-3f

// ---------------------------------------------------------------------------
// GEMM: Y[n][o] = act( sum_i X[n][i] * W[o][i] + bias[o] )
// X: (NTOK x 1024) row-major, W: (1024 x 1024) row-major (torch Linear weight)
// act: 0 = none, 1 = silu
// Tile: 64 rows x 64 cols, BK = 32, 256 threads, 4x4 acc per thread.
// ---------------------------------------------------------------------------
__global__ __launch_bounds__(256)
void gemm_nt(const float* __restrict__ X, const float* __restrict__ W,
             const float* __restrict__ bias, float* __restrict__ Y,
             int act) {
    // PAD = 68 floats per LDS row -> 272 B row stride (16B aligned) so float4
    // LDS reads are legal; bank spread stays <=2-way (free on gfx950).
    __shared__ float sX[32][68];
    __shared__ float sW[32][68];

    const int tid  = threadIdx.x;
    const int row0 = blockIdx.x * 64;
    const int col0 = blockIdx.y * 64;
    const int tm   = (tid & 15) << 2;   // 0..60
    const int tn   = (tid >> 4) << 2;   // 0..60

    float acc[4][4] = {{0.f}};

    for (int k0 = 0; k0 < D_MODEL; k0 += 32) {
        // Stage 64x32 subtiles of X and W, transposed into [kk][m] layout.
        // 512 float4 slots per operand; each thread handles 2.
        #pragma unroll
        for (int r = 0; r < 2; ++r) {
            int s  = tid + r * 256;
            int m  = s >> 3;            // 0..63
            int q4 = (s & 7) << 2;      // 0,4,...,28
            float4 xv = *(const float4*)(X + (size_t)(row0 + m) * D_MODEL + k0 + q4);
            sX[q4 + 0][m] = xv.x; sX[q4 + 1][m] = xv.y;
            sX[q4 + 2][m] = xv.z; sX[q4 + 3][m] = xv.w;
            float4 wv = *(const float4*)(W + (size_t)(col0 + m) * D_MODEL + k0 + q4);
            sW[q4 + 0][m] = wv.x; sW[q4 + 1][m] = wv.y;
            sW[q4 + 2][m] = wv.z; sW[q4 + 3][m] = wv.w;
        }
        __syncthreads();

        #pragma unroll
        for (int kk = 0; kk < 32; ++kk) {
            float4 a = *(const float4*)&sX[kk][tm];
            float4 b = *(const float4*)&sW[kk][tn];
            float av[4] = {a.x, a.y, a.z, a.w};
            float bv[4] = {b.x, b.y, b.z, b.w};
            #pragma unroll
            for (int i = 0; i < 4; ++i)
                #pragma unroll
                for (int j = 0; j < 4; ++j)
                    acc[i][j] += av[i] * bv[j];
        }
        __syncthreads();
    }

    #pragma unroll
    for (int i = 0; i < 4; ++i) {
        #pragma unroll
        for (int j = 0; j < 4; ++j) {
            float vv = acc[i][j] + bias[col0 + tn + j];
            if (act) vv = vv / (1.f + expf(-vv));   // silu
            Y[(size_t)(row0 + tm + i) * D_MODEL + col0 + tn + j] = vv;
        }
    }
}

// ---------------------------------------------------------------------------
// Per-chunk stats: kv[b,h,n][f][e] = sum_j k[j][f]*v[j][e]; ksum[b,h,n][f].
// One block per (b,h,n) = 1024 blocks, 256 threads.
// ---------------------------------------------------------------------------
__global__ __launch_bounds__(256)
void chunk_stats(const float* __restrict__ K, const float* __restrict__ V,
                 float* __restrict__ kv, float* __restrict__ ksum) {
    const int blk = blockIdx.x;
    const int n   = blk % NCHUNK;
    const int bh  = blk / NCHUNK;
    const int h   = bh % HEADS;
    const int b   = bh / HEADS;

    __shared__ float sk[CHUNK][HDIM];   // 32 KB
    __shared__ float sv[CHUNK][HDIM];   // 32 KB

    const size_t base = ((size_t)b * L_SEQ + (size_t)n * CHUNK) * D_MODEL + (size_t)h * HDIM;
    const float* Kb = K + base;
    const float* Vb = V + base;

    for (int idx = threadIdx.x; idx < CHUNK * HDIM; idx += 256) {
        int j = idx >> 6, f = idx & 63;
        sk[j][f] = Kb[(size_t)j * D_MODEL + f];
        sv[j][f] = Vb[(size_t)j * D_MODEL + f];
    }
    __syncthreads();

    const int e  = threadIdx.x & 63;
    const int f0 = threadIdx.x >> 6;    // 0..3
    float* outp = kv + (size_t)blk * HDIM * HDIM;
    for (int f = f0; f < HDIM; f += 4) {
        float acc = 0.f;
        #pragma unroll 8
        for (int j = 0; j < CHUNK; ++j) acc += sk[j][f] * sv[j][e];
        outp[f * HDIM + e] = acc;
    }
    if (threadIdx.x < HDIM) {
        int f = threadIdx.x;
        float s = 0.f;
        #pragma unroll 8
        for (int j = 0; j < CHUNK; ++j) s += sk[j][f];
        ksum[(size_t)blk * HDIM + f] = s;
    }
}

// ---------------------------------------------------------------------------
// Exclusive cumsum over chunk axis, in place. One block per (b,h) = 64 blocks.
// kv becomes S (exclusive), ksum becomes z (exclusive).
// ---------------------------------------------------------------------------
__global__ __launch_bounds__(256)
void scan_chunks(float* __restrict__ kv, float* __restrict__ ksum) {
    const int bh = blockIdx.x;
    float* base = kv + (size_t)bh * NCHUNK * HDIM * HDIM;
    for (int idx = threadIdx.x; idx < HDIM * HDIM; idx += 256) {
        float run = 0.f;
        #pragma unroll
        for (int nn = 0; nn < NCHUNK; ++nn) {
            float t = base[(size_t)nn * HDIM * HDIM + idx];
            base[(size_t)nn * HDIM * HDIM + idx] = run;
            run += t;
        }
    }
    float* zb = ksum + (size_t)bh * NCHUNK * HDIM;
    for (int idx = threadIdx.x; idx < HDIM; idx += 256) {
        float run = 0.f;
        #pragma unroll
        for (int nn = 0; nn < NCHUNK; ++nn) {
            float t = zb[nn * HDIM + idx];
            zb[nn * HDIM + idx] = run;
            run += t;
        }
    }
}

// ---------------------------------------------------------------------------
// Intra-chunk causal attention + inter-chunk state application.
// One block per (b,h,n) = 1024 blocks, 256 threads.
// num_i = sum_{j<=i} (q_i . k_j) v_j + q_i . S
// den_i = sum_{j<=i} (q_i . k_j)     + q_i . z   (== q.kcum_local + q.z)
// out_i = num_i / max(den_i, eps)
// ---------------------------------------------------------------------------
__global__ __launch_bounds__(256)
void attn_intra(const float* __restrict__ Q, const float* __restrict__ K,
                const float* __restrict__ V, const float* __restrict__ S,
                const float* __restrict__ Z, float* __restrict__ O) {
    const int blk = blockIdx.x;
    const int n   = blk % NCHUNK;
    const int bh  = blk / NCHUNK;
    const int h   = bh % HEADS;
    const int b   = bh / HEADS;

    __shared__ float sk[CHUNK][HDIM + 1];   // 33280 B, +1 pad kills stride-65->bank spread
    __shared__ float sq[32][HDIM + 1];      //  8320 B
    __shared__ float ssc[32][CHUNK];        // 16384 B   (total 57984 < 64K)

    const size_t base = ((size_t)b * L_SEQ + (size_t)n * CHUNK) * D_MODEL + (size_t)h * HDIM;
    const float* Qb = Q + base;
    const float* Kb = K + base;
    const float* Vb = V + base;
    const float* Sb = S + (size_t)blk * HDIM * HDIM;
    const float* Zb = Z + (size_t)blk * HDIM;
    float*       Ob = O + base;

    const int tid = threadIdx.x;

    for (int idx = tid; idx < CHUNK * HDIM; idx += 256) {
        int j = idx >> 6, f = idx & 63;
        sk[j][f] = Kb[(size_t)j * D_MODEL + f];
    }
    __syncthreads();

    for (int rt = 0; rt < 4; ++rt) {            // row tiles of 32
        // load q tile
        for (int idx = tid; idx < 32 * HDIM; idx += 256) {
            int i = idx >> 6, f = idx & 63;
            sq[i][f] = Qb[(size_t)(rt * 32 + i) * D_MODEL + f];
        }
        __syncthreads();

        // scores (causal-masked)
        for (int idx = tid; idx < 32 * CHUNK; idx += 256) {
            int i = idx >> 7, j = idx & 127;
            int ig = rt * 32 + i;
            float sc = 0.f;
            if (j <= ig) {
                #pragma unroll 8
                for (int f = 0; f < HDIM; ++f) sc += sq[i][f] * sk[j][f];
            }
            ssc[i][j] = sc;
        }
        __syncthreads();

        // num / den / output; lanes = e dim, 4 rows per pass
        const int e  = tid & 63;
        const int iw = tid >> 6;
        for (int p = 0; p < 8; ++p) {
            int i  = (p << 2) + iw;
            int ig = rt * 32 + i;
            float num = 0.f, den = 0.f;
            for (int j = 0; j <= ig; ++j) {
                float s = ssc[i][j];
                num += s * Vb[(size_t)j * D_MODEL + e];
                den += s;
            }
            float qz = 0.f;
            #pragma unroll 8
            for (int f = 0; f < HDIM; ++f) {
                float qf = sq[i][f];
                num += qf * Sb[(f << 6) + e];
                qz  += qf * Zb[f];
            }
            den += qz;
            Ob[(size_t)ig * D_MODEL + e] = num / fmaxf(den, EPS_DEN);
        }
        __syncthreads();
    }
}

// ---------------------------------------------------------------------------
extern "C" void kernel_launch(void* const* d_in, const int* in_sizes, int n_in,
                              void* d_out, int out_size, void* d_ws, size_t ws_size,
                              hipStream_t stream) {
    const float* x  = (const float*)d_in[0];
    const float* Wq = (const float*)d_in[1];
    const float* bq = (const float*)d_in[2];
    const float* Wk = (const float*)d_in[3];
    const float* bk = (const float*)d_in[4];
    const float* Wv = (const float*)d_in[5];
    const float* bv = (const float*)d_in[6];
    const float* Wo = (const float*)d_in[7];
    const float* bo = (const float*)d_in[8];
    float* out = (float*)d_out;

    // Workspace layout (floats): q | k | v | attn | kv(S) | ksum(z)
    const size_t NQ = (size_t)NTOK * D_MODEL;                       // 8.39M
    const size_t NKV = (size_t)B_SZ * HEADS * NCHUNK * HDIM * HDIM; // 4.19M
    float* q    = (float*)d_ws;
    float* k    = q + NQ;
    float* v    = k + NQ;
    float* attn = v + NQ;
    float* kv   = attn + NQ;
    float* ksum = kv + NKV;
    // total = 4*NQ + NKV + 64K floats ~= 151 MB

    dim3 gg(NTOK / 64, D_MODEL / 64);   // 128 x 16
    gemm_nt<<<gg, 256, 0, stream>>>(x, Wq, bq, q, 1);
    gemm_nt<<<gg, 256, 0, stream>>>(x, Wk, bk, k, 1);
    gemm_nt<<<gg, 256, 0, stream>>>(x, Wv, bv, v, 0);

    chunk_stats<<<B_SZ * HEADS * NCHUNK, 256, 0, stream>>>(k, v, kv, ksum);
    scan_chunks<<<B_SZ * HEADS, 256, 0, stream>>>(kv, ksum);
    attn_intra<<<B_SZ * HEADS * NCHUNK, 256, 0, stream>>>(q, k, v, kv, ksum, attn);

    gemm_nt<<<gg, 256, 0, stream>>>(attn, Wo, bo, out, 0);
}

// Round 2
// 515.975 us; speedup vs baseline: 2.8293x; 2.8293x over previous
//
#include <hip/hip_runtime.h>
#include <math.h>

#define D_MODEL 1024
#define HEADS   16
#define HDIM    64
#define CHUNK   128
#define B_SZ    4
#define L_SEQ   2048
#define NCHUNK  16
#define NTOK    8192
#define EPS_DEN 1e-3f

typedef _Float16 half8 __attribute__((ext_vector_type(8)));
typedef float    f32x4 __attribute__((ext_vector_type(4)));

__device__ __forceinline__ void gld_lds16(const void* g, void* l) {
    __builtin_amdgcn_global_load_lds(
        (const __attribute__((address_space(1))) void*)g,
        (__attribute__((address_space(3))) void*)l, 16, 0, 0);
}

// ---------------------------------------------------------------------------
// Split fp32 -> [hi(f16) | lo(f16)] with row stride 2048 (for x, Wq, Wk).
// total8 = rows * 1024 / 8.
// ---------------------------------------------------------------------------
__global__ __launch_bounds__(256) void split_hi_lo(const float* __restrict__ X,
                                                   _Float16* __restrict__ O, int total8) {
    int t = blockIdx.x * 256 + threadIdx.x;
    if (t >= total8) return;
    int m  = t >> 7;
    int kc = (t & 127) << 3;
    const float* src = X + (size_t)m * 1024 + kc;
    f32x4 a = *(const f32x4*)src;
    f32x4 b = *(const f32x4*)(src + 4);
    float xs[8] = {a.x, a.y, a.z, a.w, b.x, b.y, b.z, b.w};
    half8 hi, lo;
    #pragma unroll
    for (int u = 0; u < 8; ++u) {
        _Float16 h = (_Float16)xs[u];
        hi[u] = h;
        lo[u] = (_Float16)(xs[u] - (float)h);
    }
    *(half8*)(O + (size_t)m * 2048 + kc)        = hi;
    *(half8*)(O + (size_t)m * 2048 + 1024 + kc) = lo;
}

// Plain fp32 -> f16 convert, row stride 1024 (for Wv, Wo).
__global__ __launch_bounds__(256) void conv_f16(const float* __restrict__ X,
                                                _Float16* __restrict__ O, int total8) {
    int t = blockIdx.x * 256 + threadIdx.x;
    if (t >= total8) return;
    int m  = t >> 7;
    int kc = (t & 127) << 3;
    const float* src = X + (size_t)m * 1024 + kc;
    f32x4 a = *(const f32x4*)src;
    f32x4 b = *(const f32x4*)(src + 4);
    float xs[8] = {a.x, a.y, a.z, a.w, b.x, b.y, b.z, b.w};
    half8 hi;
    #pragma unroll
    for (int u = 0; u < 8; ++u) hi[u] = (_Float16)xs[u];
    *(half8*)(O + (size_t)m * 1024 + kc) = hi;
}

// ---------------------------------------------------------------------------
// f16 MFMA GEMM: Y[m][n] = act( outscale * sum_k A'[m][k]*B'[n][k] + bias[n] )
// Tile 128x128, BK=32, 256 threads (4 waves, each 64x64 via 4x4 16x16x32 MFMA).
// MODE 0: A' col = k (lda arbitrary), B' col = k.
// MODE 1 (split, K=3072 logical): A cols [hi|lo|hi] from [hi|lo] storage,
//         B cols [hi|hi|lo] from [hi|lo] storage.
// ---------------------------------------------------------------------------
template<int KITERS, int MODE, int ACT>
__global__ __launch_bounds__(256) void gemm_f16(
    const _Float16* __restrict__ A, int lda,
    const _Float16* __restrict__ B, int ldb,
    const float* __restrict__ bias,
    float* __restrict__ Y, float outscale) {
    __shared__ __align__(16) _Float16 sA[4096];  // 128 rows x 32 k
    __shared__ __align__(16) _Float16 sB[4096];

    const int tid  = threadIdx.x;
    const int lane = tid & 63;
    const int w    = tid >> 6;
    const int row0 = blockIdx.x * 128;
    const int col0 = blockIdx.y * 128;
    const int wm   = (w & 1) * 64;
    const int wn   = (w >> 1) * 64;

    // staging: chunk ch holds (row r = ch>>2, phys k-slot ch&3); logical k-chunk
    // is XOR-swizzled by (r>>1)&3 to spread ds_read banks.
    const int ch0 = w * 64 + lane;
    const int rS0 = ch0 >> 2;
    const int cS0 = (ch0 & 3) ^ ((rS0 >> 1) & 3);
    const int ch1 = ch0 + 256;
    const int rS1 = ch1 >> 2;
    const int cS1 = (ch1 & 3) ^ ((rS1 >> 1) & 3);

    f32x4 acc[4][4];
    #pragma unroll
    for (int i = 0; i < 4; ++i)
        #pragma unroll
        for (int j = 0; j < 4; ++j) { f32x4 z = {0.f, 0.f, 0.f, 0.f}; acc[i][j] = z; }

    const int ml = lane & 15;
    const int kg = lane >> 4;
    int offA[4], offB[4];
    #pragma unroll
    for (int i = 0; i < 4; ++i) {
        int r  = wm + i * 16 + ml;
        offA[i] = r * 32 + (kg ^ ((r >> 1) & 3)) * 8;
        int rn = wn + i * 16 + ml;
        offB[i] = rn * 32 + (kg ^ ((rn >> 1) & 3)) * 8;
    }

    for (int kit = 0; kit < KITERS; ++kit) {
        const int k0   = kit * 32;
        const int acol = MODE ? (k0 < 2048 ? k0 : k0 - 2048) : k0;
        const int bcol = MODE ? (k0 < 1024 ? k0 : k0 - 1024) : k0;

        gld_lds16(A + (size_t)(row0 + rS0) * lda + acol + cS0 * 8, &sA[w * 512]);
        gld_lds16(A + (size_t)(row0 + rS1) * lda + acol + cS1 * 8, &sA[2048 + w * 512]);
        gld_lds16(B + (size_t)(col0 + rS0) * ldb + bcol + cS0 * 8, &sB[w * 512]);
        gld_lds16(B + (size_t)(col0 + rS1) * ldb + bcol + cS1 * 8, &sB[2048 + w * 512]);
        __syncthreads();

        half8 af[4], bf[4];
        #pragma unroll
        for (int i = 0; i < 4; ++i) {
            af[i] = *(const half8*)&sA[offA[i]];
            bf[i] = *(const half8*)&sB[offB[i]];
        }
        #pragma unroll
        for (int i = 0; i < 4; ++i)
            #pragma unroll
            for (int j = 0; j < 4; ++j)
                acc[i][j] = __builtin_amdgcn_mfma_f32_16x16x32_f16(af[i], bf[j], acc[i][j], 0, 0, 0);
        __syncthreads();
    }

    // epilogue: C/D layout col = lane&15, row = (lane>>4)*4 + t
    const int rg = lane >> 4;
    #pragma unroll
    for (int j = 0; j < 4; ++j) {
        const int nn = col0 + wn + j * 16 + ml;
        const float bv = bias[nn];
        #pragma unroll
        for (int i = 0; i < 4; ++i) {
            #pragma unroll
            for (int t = 0; t < 4; ++t) {
                int mm = row0 + wm + i * 16 + rg * 4 + t;
                float vv = acc[i][j][t] * outscale + bv;
                if (ACT) vv = vv / (1.f + expf(-vv));
                Y[(size_t)mm * 1024 + nn] = vv;
            }
        }
    }
}

// ---------------------------------------------------------------------------
// Per-chunk stats: kv[blk][f][e] = sum_j k[j][f]*v[j][e]; ksum[blk][f].
// ---------------------------------------------------------------------------
__global__ __launch_bounds__(256) void chunk_stats(const float* __restrict__ K,
                                                   const float* __restrict__ V,
                                                   float* __restrict__ kv,
                                                   float* __restrict__ ksum) {
    const int blk = blockIdx.x;
    const int n = blk & 15, bh = blk >> 4, h = bh & 15, b = bh >> 4;
    __shared__ float sk[128 * 64];
    __shared__ float sv[128 * 64];
    const size_t base = ((size_t)b * L_SEQ + (size_t)n * CHUNK) * D_MODEL + (size_t)h * HDIM;

    for (int t = threadIdx.x; t < 2048; t += 256) {
        int j = t >> 4, fc = (t & 15) * 4;
        *(f32x4*)&sk[j * 64 + fc] = *(const f32x4*)(K + base + (size_t)j * D_MODEL + fc);
        *(f32x4*)&sv[j * 64 + fc] = *(const f32x4*)(V + base + (size_t)j * D_MODEL + fc);
    }
    __syncthreads();

    const int tf = threadIdx.x >> 4, te = threadIdx.x & 15;
    f32x4 a0 = {0.f,0.f,0.f,0.f}, a1 = a0, a2 = a0, a3 = a0;
    for (int j = 0; j < 128; ++j) {
        f32x4 kf = *(const f32x4*)&sk[j * 64 + tf * 4];
        f32x4 vf = *(const f32x4*)&sv[j * 64 + te * 4];
        a0 += kf.x * vf; a1 += kf.y * vf; a2 += kf.z * vf; a3 += kf.w * vf;
    }
    float* o = kv + (size_t)blk * 4096;
    *(f32x4*)&o[(tf * 4 + 0) * 64 + te * 4] = a0;
    *(f32x4*)&o[(tf * 4 + 1) * 64 + te * 4] = a1;
    *(f32x4*)&o[(tf * 4 + 2) * 64 + te * 4] = a2;
    *(f32x4*)&o[(tf * 4 + 3) * 64 + te * 4] = a3;

    if (threadIdx.x < 64) {
        float s = 0.f;
        #pragma unroll 8
        for (int j = 0; j < 128; ++j) s += sk[j * 64 + threadIdx.x];
        ksum[(size_t)blk * 64 + threadIdx.x] = s;
    }
}

// ---------------------------------------------------------------------------
// Exclusive cumsum over chunk axis, in place.
// ---------------------------------------------------------------------------
__global__ __launch_bounds__(256) void scan_chunks(float* __restrict__ kv,
                                                   float* __restrict__ ksum) {
    const int bh = blockIdx.x;
    float* base = kv + (size_t)bh * NCHUNK * 4096;
    for (int idx = threadIdx.x; idx < 4096; idx += 256) {
        float run = 0.f;
        #pragma unroll
        for (int nn = 0; nn < NCHUNK; ++nn) {
            float t = base[(size_t)nn * 4096 + idx];
            base[(size_t)nn * 4096 + idx] = run;
            run += t;
        }
    }
    float* zb = ksum + (size_t)bh * NCHUNK * 64;
    for (int idx = threadIdx.x; idx < 64; idx += 256) {
        float run = 0.f;
        #pragma unroll
        for (int nn = 0; nn < NCHUNK; ++nn) {
            float t = zb[nn * 64 + idx];
            zb[nn * 64 + idx] = run;
            run += t;
        }
    }
}

// ---------------------------------------------------------------------------
// Attention core. den path entirely fp32 (precision-critical near den~eps);
// num path uses f16 scores/S. Output written as f16 * (1/64) for final GEMM.
// 512 threads, LDS < 64KB (2 blocks/CU).
// ---------------------------------------------------------------------------
__global__ __launch_bounds__(512) void attn_core(
    const float* __restrict__ Q, const float* __restrict__ K,
    const float* __restrict__ V, const float* __restrict__ S,
    const float* __restrict__ Z, _Float16* __restrict__ O16) {
    const int blk = blockIdx.x;
    const int n = blk & 15, bh = blk >> 4, h = bh & 15, b = bh >> 4;

    __shared__ float    sk[128 * 68];     // 34816 B, stride 17 granules (odd)
    __shared__ float    sq[32 * 68];      //  8704 B
    __shared__ _Float16 sS16[64 * 64];    //  8192 B  [f][e]
    __shared__ __align__(16) _Float16 ssc[32 * 136];  // 8704 B, half8-aligned rows
    __shared__ float    sden[32 * 17];    //  2176 B
    __shared__ float    sz[64];           //   256 B
    __shared__ float    dden[32];         //   128 B

    const size_t base = ((size_t)b * L_SEQ + (size_t)n * CHUNK) * D_MODEL + (size_t)h * HDIM;
    const float* Qb = Q + base;
    const float* Kb = K + base;
    const float* Vb = V + base;
    const float* Sb = S + (size_t)blk * 4096;
    const float* Zb = Z + (size_t)blk * 64;

    const int tid = threadIdx.x;

    for (int t = tid; t < 2048; t += 512) {
        int j = t >> 4, fc = (t & 15) * 4;
        *(f32x4*)&sk[j * 68 + fc] = *(const f32x4*)(Kb + (size_t)j * D_MODEL + fc);
    }
    for (int t = tid; t < 4096; t += 512) sS16[t] = (_Float16)Sb[t];
    if (tid < 64) sz[tid] = Zb[tid];
    __syncthreads();

    for (int rt = 0; rt < 4; ++rt) {
        {   // q tile: 32 rows
            int t = tid;  // exactly 512 f32x4 chunks
            int i = t >> 4, fc = (t & 15) * 4;
            *(f32x4*)&sq[i * 68 + fc] = *(const f32x4*)(Qb + (size_t)(rt * 32 + i) * D_MODEL + fc);
        }
        __syncthreads();

        // scores: thread -> row i = tid>>4, j in {j0 + 16u}, fp32 den partial
        {
            const int i  = tid >> 4;       // 0..31
            const int j0 = tid & 15;
            const int ig = rt * 32 + i;
            float dpart = 0.f;
            #pragma unroll
            for (int u = 0; u < 8; ++u) {
                int j = j0 + 16 * u;
                float sc = 0.f;
                if (j <= ig) {
                    f32x4 vacc = {0.f, 0.f, 0.f, 0.f};
                    #pragma unroll
                    for (int fc = 0; fc < 64; fc += 4) {
                        f32x4 a  = *(const f32x4*)&sq[i * 68 + fc];
                        f32x4 bb = *(const f32x4*)&sk[j * 68 + fc];
                        vacc += a * bb;
                    }
                    sc = vacc.x + vacc.y + vacc.z + vacc.w;
                }
                ssc[i * 136 + j] = (_Float16)sc;
                dpart += sc;
            }
            sden[i * 17 + j0] = dpart;
        }
        __syncthreads();

        // den reduce + q.z (fp32, exact path)
        if (tid < 32) {
            float ds = 0.f;
            #pragma unroll
            for (int g = 0; g < 16; ++g) ds += sden[tid * 17 + g];
            #pragma unroll
            for (int fc = 0; fc < 64; fc += 4) {
                f32x4 qf = *(const f32x4*)&sq[tid * 68 + fc];
                f32x4 zf = *(const f32x4*)&sz[fc];
                ds += qf.x * zf.x + qf.y * zf.y + qf.z * zf.z + qf.w * zf.w;
            }
            dden[tid] = ds;
        }
        __syncthreads();

        // num: e lanes, 4 rows per thread
        {
            const int e  = tid & 63;
            const int iw = tid >> 6;
            for (int ii = 0; ii < 4; ++ii) {
                const int i  = iw + ii * 8;
                const int ig = rt * 32 + i;
                float num = 0.f;
                const float* vp = Vb + e;
                for (int j = 0; j <= ig; j += 8) {
                    half8 s8 = *(const half8*)&ssc[i * 136 + j];
                    const float* vj = vp + (size_t)j * D_MODEL;
                    num += (float)s8[0] * vj[0]
                         + (float)s8[1] * vj[D_MODEL]
                         + (float)s8[2] * vj[2 * D_MODEL]
                         + (float)s8[3] * vj[3 * D_MODEL]
                         + (float)s8[4] * vj[4 * D_MODEL]
                         + (float)s8[5] * vj[5 * D_MODEL]
                         + (float)s8[6] * vj[6 * D_MODEL]
                         + (float)s8[7] * vj[7 * D_MODEL];
                }
                #pragma unroll
                for (int fc = 0; fc < 64; fc += 4) {
                    f32x4 qf = *(const f32x4*)&sq[i * 68 + fc];
                    num += qf.x * (float)sS16[(fc + 0) * 64 + e]
                         + qf.y * (float)sS16[(fc + 1) * 64 + e]
                         + qf.z * (float)sS16[(fc + 2) * 64 + e]
                         + qf.w * (float)sS16[(fc + 3) * 64 + e];
                }
                float den = dden[i];
                float o = num / fmaxf(den, EPS_DEN);
                O16[base + (size_t)ig * D_MODEL + e] = (_Float16)(o * 0.015625f);
            }
        }
        __syncthreads();
    }
}

// ---------------------------------------------------------------------------
extern "C" void kernel_launch(void* const* d_in, const int* in_sizes, int n_in,
                              void* d_out, int out_size, void* d_ws, size_t ws_size,
                              hipStream_t stream) {
    const float* x  = (const float*)d_in[0];
    const float* Wq = (const float*)d_in[1];
    const float* bq = (const float*)d_in[2];
    const float* Wk = (const float*)d_in[3];
    const float* bk = (const float*)d_in[4];
    const float* Wv = (const float*)d_in[5];
    const float* bv = (const float*)d_in[6];
    const float* Wo = (const float*)d_in[7];
    const float* bo = (const float*)d_in[8];
    float* out = (float*)d_out;

    // workspace layout (bytes)
    char* p = (char*)d_ws;
    _Float16* x2   = (_Float16*)p;  p += (size_t)NTOK * 2048 * 2;     // 33.6 MB
    _Float16* w2q  = (_Float16*)p;  p += (size_t)1024 * 2048 * 2;     //  4.2 MB
    _Float16* w2k  = (_Float16*)p;  p += (size_t)1024 * 2048 * 2;
    _Float16* wv16 = (_Float16*)p;  p += (size_t)1024 * 1024 * 2;     //  2.1 MB
    _Float16* wo16 = (_Float16*)p;  p += (size_t)1024 * 1024 * 2;
    float* qb   = (float*)p;        p += (size_t)NTOK * 1024 * 4;     // 33.6 MB
    float* kb   = (float*)p;        p += (size_t)NTOK * 1024 * 4;
    float* vb   = (float*)p;        p += (size_t)NTOK * 1024 * 4;
    float* kvb  = (float*)p;        p += (size_t)1024 * 4096 * 4;     // 16.8 MB
    float* ksb  = (float*)p;        p += (size_t)1024 * 64 * 4;       //  0.26 MB
    _Float16* attn16 = x2;  // alias: x2 dead after the 3 projection GEMMs

    split_hi_lo<<<4096, 256, 0, stream>>>(x, x2, NTOK * 128);
    split_hi_lo<<<512, 256, 0, stream>>>(Wq, w2q, 1024 * 128);
    split_hi_lo<<<512, 256, 0, stream>>>(Wk, w2k, 1024 * 128);
    conv_f16<<<512, 256, 0, stream>>>(Wv, wv16, 1024 * 128);
    conv_f16<<<512, 256, 0, stream>>>(Wo, wo16, 1024 * 128);

    dim3 gg(NTOK / 128, 1024 / 128);  // 64 x 8
    gemm_f16<96, 1, 1><<<gg, 256, 0, stream>>>(x2, 2048, w2q, 2048, bq, qb, 1.f);
    gemm_f16<96, 1, 1><<<gg, 256, 0, stream>>>(x2, 2048, w2k, 2048, bk, kb, 1.f);
    gemm_f16<32, 0, 0><<<gg, 256, 0, stream>>>(x2, 2048, wv16, 1024, bv, vb, 1.f);

    chunk_stats<<<1024, 256, 0, stream>>>(kb, vb, kvb, ksb);
    scan_chunks<<<64, 256, 0, stream>>>(kvb, ksb);
    attn_core<<<1024, 512, 0, stream>>>(qb, kb, vb, kvb, ksb, attn16);

    gemm_f16<32, 0, 0><<<gg, 256, 0, stream>>>(attn16, 1024, wo16, 1024, bo, out, 64.f);
}

// Round 3
// 378.945 us; speedup vs baseline: 3.8524x; 1.3616x over previous
//
#include <hip/hip_runtime.h>
#include <math.h>

#define D_MODEL 1024
#define HEADS   16
#define HDIM    64
#define CHUNK   128
#define B_SZ    4
#define L_SEQ   2048
#define NCHUNK  16
#define NTOK    8192
#define EPS_DEN 1e-3f

typedef _Float16 half8 __attribute__((ext_vector_type(8)));
typedef float    f32x4 __attribute__((ext_vector_type(4)));

__device__ __forceinline__ void gld_lds16(const void* g, void* l) {
    __builtin_amdgcn_global_load_lds(
        (const __attribute__((address_space(1))) void*)g,
        (__attribute__((address_space(3))) void*)l, 16, 0, 0);
}

// ---------------------------------------------------------------------------
// fp32 -> [hi(f16) | lo(f16)], row stride 2048 (x, Wq, Wk).
// ---------------------------------------------------------------------------
__global__ __launch_bounds__(256) void split_hi_lo(const float* __restrict__ X,
                                                   _Float16* __restrict__ O, int total8) {
    int t = blockIdx.x * 256 + threadIdx.x;
    if (t >= total8) return;
    int m  = t >> 7;
    int kc = (t & 127) << 3;
    const float* src = X + (size_t)m * 1024 + kc;
    f32x4 a = *(const f32x4*)src;
    f32x4 b = *(const f32x4*)(src + 4);
    float xs[8] = {a.x, a.y, a.z, a.w, b.x, b.y, b.z, b.w};
    half8 hi, lo;
    #pragma unroll
    for (int u = 0; u < 8; ++u) {
        _Float16 h = (_Float16)xs[u];
        hi[u] = h;
        lo[u] = (_Float16)(xs[u] - (float)h);
    }
    *(half8*)(O + (size_t)m * 2048 + kc)        = hi;
    *(half8*)(O + (size_t)m * 2048 + 1024 + kc) = lo;
}

__global__ __launch_bounds__(256) void conv_f16(const float* __restrict__ X,
                                                _Float16* __restrict__ O, int total8) {
    int t = blockIdx.x * 256 + threadIdx.x;
    if (t >= total8) return;
    int m  = t >> 7;
    int kc = (t & 127) << 3;
    const float* src = X + (size_t)m * 1024 + kc;
    f32x4 a = *(const f32x4*)src;
    f32x4 b = *(const f32x4*)(src + 4);
    float xs[8] = {a.x, a.y, a.z, a.w, b.x, b.y, b.z, b.w};
    half8 hi;
    #pragma unroll
    for (int u = 0; u < 8; ++u) hi[u] = (_Float16)xs[u];
    *(half8*)(O + (size_t)m * 1024 + kc) = hi;
}

// ---------------------------------------------------------------------------
// f16 MFMA GEMM, tile 128x128, BK=32. W32/W16 select fp32 and/or f16 outputs.
// ---------------------------------------------------------------------------
template<int KITERS, int MODE, int ACT, int W32, int W16>
__global__ __launch_bounds__(256) void gemm_f16(
    const _Float16* __restrict__ A, int lda,
    const _Float16* __restrict__ B, int ldb,
    const float* __restrict__ bias,
    float* __restrict__ Y32, _Float16* __restrict__ Y16, float outscale) {
    __shared__ __align__(16) _Float16 sA[4096];
    __shared__ __align__(16) _Float16 sB[4096];

    const int tid  = threadIdx.x;
    const int lane = tid & 63;
    const int w    = tid >> 6;
    const int row0 = blockIdx.x * 128;
    const int col0 = blockIdx.y * 128;
    const int wm   = (w & 1) * 64;
    const int wn   = (w >> 1) * 64;

    const int ch0 = w * 64 + lane;
    const int rS0 = ch0 >> 2;
    const int cS0 = (ch0 & 3) ^ ((rS0 >> 1) & 3);
    const int ch1 = ch0 + 256;
    const int rS1 = ch1 >> 2;
    const int cS1 = (ch1 & 3) ^ ((rS1 >> 1) & 3);

    f32x4 acc[4][4];
    #pragma unroll
    for (int i = 0; i < 4; ++i)
        #pragma unroll
        for (int j = 0; j < 4; ++j) { f32x4 z = {0.f, 0.f, 0.f, 0.f}; acc[i][j] = z; }

    const int ml = lane & 15;
    const int kg = lane >> 4;
    int offA[4], offB[4];
    #pragma unroll
    for (int i = 0; i < 4; ++i) {
        int r  = wm + i * 16 + ml;
        offA[i] = r * 32 + (kg ^ ((r >> 1) & 3)) * 8;
        int rn = wn + i * 16 + ml;
        offB[i] = rn * 32 + (kg ^ ((rn >> 1) & 3)) * 8;
    }

    for (int kit = 0; kit < KITERS; ++kit) {
        const int k0   = kit * 32;
        const int acol = MODE ? (k0 < 2048 ? k0 : k0 - 2048) : k0;
        const int bcol = MODE ? (k0 < 1024 ? k0 : k0 - 1024) : k0;

        gld_lds16(A + (size_t)(row0 + rS0) * lda + acol + cS0 * 8, &sA[w * 512]);
        gld_lds16(A + (size_t)(row0 + rS1) * lda + acol + cS1 * 8, &sA[2048 + w * 512]);
        gld_lds16(B + (size_t)(col0 + rS0) * ldb + bcol + cS0 * 8, &sB[w * 512]);
        gld_lds16(B + (size_t)(col0 + rS1) * ldb + bcol + cS1 * 8, &sB[2048 + w * 512]);
        __syncthreads();

        half8 af[4], bf[4];
        #pragma unroll
        for (int i = 0; i < 4; ++i) {
            af[i] = *(const half8*)&sA[offA[i]];
            bf[i] = *(const half8*)&sB[offB[i]];
        }
        #pragma unroll
        for (int i = 0; i < 4; ++i)
            #pragma unroll
            for (int j = 0; j < 4; ++j)
                acc[i][j] = __builtin_amdgcn_mfma_f32_16x16x32_f16(af[i], bf[j], acc[i][j], 0, 0, 0);
        __syncthreads();
    }

    const int rg = lane >> 4;
    #pragma unroll
    for (int j = 0; j < 4; ++j) {
        const int nn = col0 + wn + j * 16 + ml;
        const float bv = bias[nn];
        #pragma unroll
        for (int i = 0; i < 4; ++i) {
            #pragma unroll
            for (int t = 0; t < 4; ++t) {
                int mm = row0 + wm + i * 16 + rg * 4 + t;
                float vv = acc[i][j][t] * outscale + bv;
                if (ACT) vv = vv / (1.f + expf(-vv));
                if (W32) Y32[(size_t)mm * 1024 + nn] = vv;
                if (W16) Y16[(size_t)mm * 1024 + nn] = (_Float16)vv;
            }
        }
    }
}

// ---------------------------------------------------------------------------
// chunk stats: kvT[blk][e][f] = sum_j v16[j][e]*k16[j][f] via MFMA;
// ksum[blk][f] fp32 from kf32 (precision-critical, feeds z -> den).
// ---------------------------------------------------------------------------
__global__ __launch_bounds__(256) void chunk_stats(
    const _Float16* __restrict__ k16g, const _Float16* __restrict__ v16g,
    const float* __restrict__ kf32,
    float* __restrict__ kvT, float* __restrict__ ksum) {
    const int blk = blockIdx.x;
    const int n = blk & 15, bh = blk >> 4, h = bh & 15, b = bh >> 4;
    const size_t base = ((size_t)b * L_SEQ + (size_t)n * CHUNK) * D_MODEL + (size_t)h * HDIM;

    __shared__ __align__(16) _Float16 sv[64 * 136];  // vT[e][j]
    __shared__ __align__(16) _Float16 sk[64 * 136];  // kT[f][j]
    __shared__ float sred[4 * 64];

    const int tid = threadIdx.x;
    #pragma unroll
    for (int p = 0; p < 4; ++p) {
        int idx = p * 256 + tid;
        int j = idx >> 3, c = idx & 7;
        half8 vv = *(const half8*)(v16g + base + (size_t)j * D_MODEL + c * 8);
        half8 kk = *(const half8*)(k16g + base + (size_t)j * D_MODEL + c * 8);
        #pragma unroll
        for (int u = 0; u < 8; ++u) {
            sv[(c * 8 + u) * 136 + j] = vv[u];
            sk[(c * 8 + u) * 136 + j] = kk[u];
        }
    }
    __syncthreads();

    const int lane = tid & 63;
    const int w    = tid >> 6;
    const int ml   = lane & 15;
    const int kg   = lane >> 4;

    f32x4 acc[4];
    #pragma unroll
    for (int ft = 0; ft < 4; ++ft) { f32x4 z = {0.f,0.f,0.f,0.f}; acc[ft] = z; }
    #pragma unroll
    for (int ft = 0; ft < 4; ++ft)
        #pragma unroll
        for (int kit = 0; kit < 4; ++kit) {
            half8 af = *(const half8*)&sv[(w * 16 + ml) * 136 + kit * 32 + kg * 8];
            half8 bf = *(const half8*)&sk[(ft * 16 + ml) * 136 + kit * 32 + kg * 8];
            acc[ft] = __builtin_amdgcn_mfma_f32_16x16x32_f16(af, bf, acc[ft], 0, 0, 0);
        }
    float* o = kvT + (size_t)blk * 4096;
    #pragma unroll
    for (int ft = 0; ft < 4; ++ft)
        #pragma unroll
        for (int t = 0; t < 4; ++t) {
            int e = w * 16 + kg * 4 + t;
            o[e * 64 + ft * 16 + ml] = acc[ft][t];
        }

    // ksum (fp32)
    float s = 0.f;
    for (int j = w * 32; j < w * 32 + 32; ++j)
        s += kf32[base + (size_t)j * D_MODEL + lane];
    sred[w * 64 + lane] = s;
    __syncthreads();
    if (tid < 64)
        ksum[(size_t)blk * 64 + tid] = sred[tid] + sred[64 + tid] + sred[128 + tid] + sred[192 + tid];
}

// ---------------------------------------------------------------------------
// Exclusive cumsum over chunk axis. 1024 blocks: bh = blk>>4, seg = blk&15.
// ---------------------------------------------------------------------------
__global__ __launch_bounds__(256) void scan_chunks(float* __restrict__ kvT,
                                                   float* __restrict__ ksum) {
    const int bh  = blockIdx.x >> 4;
    const int seg = blockIdx.x & 15;
    const int idx = seg * 256 + threadIdx.x;
    float* base = kvT + (size_t)bh * NCHUNK * 4096 + idx;
    float run = 0.f;
    #pragma unroll
    for (int nn = 0; nn < NCHUNK; ++nn) {
        float t = base[(size_t)nn * 4096];
        base[(size_t)nn * 4096] = run;
        run += t;
    }
    if (seg == 0 && threadIdx.x < 64) {
        float* zb = ksum + (size_t)bh * NCHUNK * 64 + threadIdx.x;
        float r2 = 0.f;
        #pragma unroll
        for (int nn = 0; nn < NCHUNK; ++nn) {
            float t = zb[nn * 64];
            zb[nn * 64] = r2;
            r2 += t;
        }
    }
}

// ---------------------------------------------------------------------------
// den[b,h,l] = q_l . (cumsum_{j<=l} k_j)  — all fp32 (precision-critical).
// One block per (b,h,n); 4 waves, each scans 32 rows after a partial-sum pass.
// ---------------------------------------------------------------------------
__global__ __launch_bounds__(256) void den_kernel(
    const float* __restrict__ qf32, const float* __restrict__ kf32,
    const float* __restrict__ zg, float* __restrict__ deng) {
    const int blk = blockIdx.x;
    const int n = blk & 15, bh = blk >> 4, h = bh & 15, b = bh >> 4;
    const size_t base = ((size_t)b * L_SEQ + (size_t)n * CHUNK) * D_MODEL + (size_t)h * HDIM;

    __shared__ float skk[128 * 64];
    __shared__ float part[4 * 64];

    const int tid = threadIdx.x;
    #pragma unroll
    for (int p = 0; p < 8; ++p) {
        int idx = p * 256 + tid;
        int j = idx >> 4, fc = (idx & 15) * 4;
        *(f32x4*)&skk[j * 64 + fc] = *(const f32x4*)(kf32 + base + (size_t)j * D_MODEL + fc);
    }
    __syncthreads();

    const int w = tid >> 6, lane = tid & 63;
    float ps = 0.f;
    for (int j = w * 32; j < w * 32 + 32; ++j) ps += skk[j * 64 + lane];
    part[w * 64 + lane] = ps;
    __syncthreads();

    float acc = zg[(size_t)blk * 64 + lane];
    for (int w2 = 0; w2 < w; ++w2) acc += part[w2 * 64 + lane];

    float* dout = deng + ((size_t)(b * 16 + h)) * L_SEQ + n * CHUNK;
    for (int jj = 0; jj < 32; ++jj) {
        int j = w * 32 + jj;
        acc += skk[j * 64 + lane];
        float d = qf32[base + (size_t)j * D_MODEL + lane] * acc;
        #pragma unroll
        for (int off = 32; off > 0; off >>= 1) d += __shfl_xor(d, off, 64);
        if (lane == 0) dout[j] = d;
    }
}

// ---------------------------------------------------------------------------
// MFMA attention core. scores = q k^T (masked, f16), num = [ssc|q]·[vT|ST],
// out = num / max(den,eps) * (1/64)  -> f16.
// 256 threads / 4 waves; each wave owns 16 score rows per half (ssc private).
// ---------------------------------------------------------------------------
__global__ __launch_bounds__(256) void attn_core(
    const _Float16* __restrict__ q16g, const _Float16* __restrict__ k16g,
    const _Float16* __restrict__ v16g, const float* __restrict__ STg,
    const float* __restrict__ deng, _Float16* __restrict__ O16) {
    const int blk = blockIdx.x;
    const int n = blk & 15, bh = blk >> 4, h = bh & 15, b = bh >> 4;
    const size_t base = ((size_t)b * L_SEQ + (size_t)n * CHUNK) * D_MODEL + (size_t)h * HDIM;

    __shared__ __align__(16) _Float16 sq [128 * 72];   // q16 [i][f]
    __shared__ __align__(16) _Float16 sk [128 * 72];   // k16 [j][f]
    __shared__ __align__(16) _Float16 sv [64 * 136];   // vT  [e][j]
    __shared__ __align__(16) _Float16 sS [64 * 72];    // ST  [e][f]
    __shared__ __align__(16) _Float16 ssc[64 * 136];   // scores (wave-private rows)
    __shared__ float sden[128];

    const int tid = threadIdx.x;
    #pragma unroll
    for (int p = 0; p < 4; ++p) {
        int idx = p * 256 + tid;
        int j = idx >> 3, c = idx & 7;
        *(half8*)&sq[j * 72 + c * 8] = *(const half8*)(q16g + base + (size_t)j * D_MODEL + c * 8);
        *(half8*)&sk[j * 72 + c * 8] = *(const half8*)(k16g + base + (size_t)j * D_MODEL + c * 8);
        half8 vv = *(const half8*)(v16g + base + (size_t)j * D_MODEL + c * 8);
        #pragma unroll
        for (int u = 0; u < 8; ++u) sv[(c * 8 + u) * 136 + j] = vv[u];
    }
    #pragma unroll
    for (int p = 0; p < 2; ++p) {
        int idx = p * 256 + tid;
        int e = idx >> 3, c = idx & 7;
        f32x4 a = *(const f32x4*)(STg + (size_t)blk * 4096 + e * 64 + c * 8);
        f32x4 bq4 = *(const f32x4*)(STg + (size_t)blk * 4096 + e * 64 + c * 8 + 4);
        half8 hv;
        hv[0] = (_Float16)a.x;  hv[1] = (_Float16)a.y;
        hv[2] = (_Float16)a.z;  hv[3] = (_Float16)a.w;
        hv[4] = (_Float16)bq4.x; hv[5] = (_Float16)bq4.y;
        hv[6] = (_Float16)bq4.z; hv[7] = (_Float16)bq4.w;
        *(half8*)&sS[e * 72 + c * 8] = hv;
    }
    if (tid < 128) sden[tid] = deng[((size_t)(b * 16 + h)) * L_SEQ + n * CHUNK + tid];
    __syncthreads();

    const int lane = tid & 63;
    const int w    = tid >> 6;
    const int ml   = lane & 15;
    const int kg   = lane >> 4;

    for (int h2 = 0; h2 < 2; ++h2) {
        const int r0 = h2 * 64 + w * 16;     // global row base of this wave's strip
        const int rowmax = r0 + 15;

        // ---- phase 1: scores rows [r0, r0+16) x cols [0,128) ----
        f32x4 acc1[8];
        #pragma unroll
        for (int nt = 0; nt < 8; ++nt) { f32x4 z = {0.f,0.f,0.f,0.f}; acc1[nt] = z; }
        #pragma unroll
        for (int nt = 0; nt < 8; ++nt) {
            if (nt * 16 <= rowmax) {
                #pragma unroll
                for (int kit = 0; kit < 2; ++kit) {
                    half8 af = *(const half8*)&sq[(r0 + ml) * 72 + kit * 32 + kg * 8];
                    half8 bf = *(const half8*)&sk[(nt * 16 + ml) * 72 + kit * 32 + kg * 8];
                    acc1[nt] = __builtin_amdgcn_mfma_f32_16x16x32_f16(af, bf, acc1[nt], 0, 0, 0);
                }
            }
        }
        // mask + f16 -> ssc (wave-private rows w*16 .. w*16+15)
        #pragma unroll
        for (int nt = 0; nt < 8; ++nt) {
            #pragma unroll
            for (int t = 0; t < 4; ++t) {
                int lr = w * 16 + kg * 4 + t;
                int ig = h2 * 64 + lr;
                int jg = nt * 16 + ml;
                float val = (jg <= ig) ? acc1[nt][t] : 0.f;
                ssc[lr * 136 + jg] = (_Float16)val;
            }
        }
        __syncthreads();   // cheap insurance; waves only touch their own rows

        // ---- phase 2: num rows [r0, r0+16) x e [0,64) ; K = [ssc(128) | q(64)] ----
        f32x4 acc2[4];
        #pragma unroll
        for (int et = 0; et < 4; ++et) { f32x4 z = {0.f,0.f,0.f,0.f}; acc2[et] = z; }
        const int nkit = (h2 == 0) ? 2 : 4;   // j-kits used
        #pragma unroll
        for (int et = 0; et < 4; ++et) {
            for (int kit = 0; kit < nkit; ++kit) {
                half8 af = *(const half8*)&ssc[(w * 16 + ml) * 136 + kit * 32 + kg * 8];
                half8 bf = *(const half8*)&sv[(et * 16 + ml) * 136 + kit * 32 + kg * 8];
                acc2[et] = __builtin_amdgcn_mfma_f32_16x16x32_f16(af, bf, acc2[et], 0, 0, 0);
            }
            #pragma unroll
            for (int kit = 0; kit < 2; ++kit) {
                half8 af = *(const half8*)&sq[(r0 + ml) * 72 + kit * 32 + kg * 8];
                half8 bf = *(const half8*)&sS[(et * 16 + ml) * 72 + kit * 32 + kg * 8];
                acc2[et] = __builtin_amdgcn_mfma_f32_16x16x32_f16(af, bf, acc2[et], 0, 0, 0);
            }
        }
        // epilogue
        #pragma unroll
        for (int t = 0; t < 4; ++t) {
            int lr = w * 16 + kg * 4 + t;
            int ig = h2 * 64 + lr;
            float rc = 0.015625f / fmaxf(sden[ig], EPS_DEN);
            #pragma unroll
            for (int et = 0; et < 4; ++et) {
                int e = et * 16 + ml;
                O16[base + (size_t)ig * D_MODEL + e] = (_Float16)(acc2[et][t] * rc);
            }
        }
        __syncthreads();
    }
}

// ---------------------------------------------------------------------------
extern "C" void kernel_launch(void* const* d_in, const int* in_sizes, int n_in,
                              void* d_out, int out_size, void* d_ws, size_t ws_size,
                              hipStream_t stream) {
    const float* x  = (const float*)d_in[0];
    const float* Wq = (const float*)d_in[1];
    const float* bq = (const float*)d_in[2];
    const float* Wk = (const float*)d_in[3];
    const float* bk = (const float*)d_in[4];
    const float* Wv = (const float*)d_in[5];
    const float* bv = (const float*)d_in[6];
    const float* Wo = (const float*)d_in[7];
    const float* bo = (const float*)d_in[8];
    float* out = (float*)d_out;

    char* p = (char*)d_ws;
    _Float16* x2   = (_Float16*)p;  p += (size_t)NTOK * 2048 * 2;     // 33.6 MB
    _Float16* w2q  = (_Float16*)p;  p += (size_t)1024 * 2048 * 2;
    _Float16* w2k  = (_Float16*)p;  p += (size_t)1024 * 2048 * 2;
    _Float16* wv16 = (_Float16*)p;  p += (size_t)1024 * 1024 * 2;
    _Float16* wo16 = (_Float16*)p;  p += (size_t)1024 * 1024 * 2;
    float* qf   = (float*)p;        p += (size_t)NTOK * 1024 * 4;     // 33.6 MB
    float* kf   = (float*)p;        p += (size_t)NTOK * 1024 * 4;
    _Float16* q16 = (_Float16*)p;   p += (size_t)NTOK * 1024 * 2;     // 16.8 MB
    _Float16* k16 = (_Float16*)p;   p += (size_t)NTOK * 1024 * 2;
    _Float16* v16 = (_Float16*)p;   p += (size_t)NTOK * 1024 * 2;
    float* kvT  = (float*)p;        p += (size_t)1024 * 4096 * 4;     // 16.8 MB
    float* ksb  = (float*)p;        p += (size_t)1024 * 64 * 4;
    float* den  = (float*)p;        p += (size_t)B_SZ * HEADS * L_SEQ * 4;
    _Float16* attn16 = x2;  // x2 dead after projection GEMMs

    split_hi_lo<<<4096, 256, 0, stream>>>(x, x2, NTOK * 128);
    split_hi_lo<<<512, 256, 0, stream>>>(Wq, w2q, 1024 * 128);
    split_hi_lo<<<512, 256, 0, stream>>>(Wk, w2k, 1024 * 128);
    conv_f16<<<512, 256, 0, stream>>>(Wv, wv16, 1024 * 128);
    conv_f16<<<512, 256, 0, stream>>>(Wo, wo16, 1024 * 128);

    dim3 gg(NTOK / 128, 1024 / 128);  // 64 x 8
    gemm_f16<96, 1, 1, 1, 1><<<gg, 256, 0, stream>>>(x2, 2048, w2q, 2048, bq, qf, q16, 1.f);
    gemm_f16<96, 1, 1, 1, 1><<<gg, 256, 0, stream>>>(x2, 2048, w2k, 2048, bk, kf, k16, 1.f);
    gemm_f16<32, 0, 0, 0, 1><<<gg, 256, 0, stream>>>(x2, 2048, wv16, 1024, bv, nullptr, v16, 1.f);

    chunk_stats<<<1024, 256, 0, stream>>>(k16, v16, kf, kvT, ksb);
    scan_chunks<<<1024, 256, 0, stream>>>(kvT, ksb);
    den_kernel<<<1024, 256, 0, stream>>>(qf, kf, ksb, den);
    attn_core<<<1024, 256, 0, stream>>>(q16, k16, v16, kvT, den, attn16);

    gemm_f16<32, 0, 0, 1, 0><<<gg, 256, 0, stream>>>(attn16, 1024, wo16, 1024, bo, out, nullptr, 64.f);
}

// Round 4
// 354.062 us; speedup vs baseline: 4.1231x; 1.0703x over previous
//
#include <hip/hip_runtime.h>
#include <math.h>

#define D_MODEL 1024
#define HEADS   16
#define HDIM    64
#define CHUNK   128
#define B_SZ    4
#define L_SEQ   2048
#define NCHUNK  16
#define NTOK    8192
#define EPS_DEN 1e-3f

typedef _Float16 half8 __attribute__((ext_vector_type(8)));
typedef float    f32x4 __attribute__((ext_vector_type(4)));

__device__ __forceinline__ void gld_lds16(const void* g, void* l) {
    __builtin_amdgcn_global_load_lds(
        (const __attribute__((address_space(1))) void*)g,
        (__attribute__((address_space(3))) void*)l, 16, 0, 0);
}

// ---------------------------------------------------------------------------
// Fused preprocessing: x->hi|lo, Wq->hi|lo, Wk->hi|lo, Wv->f16, Wo->f16,
// bias concat [bq|bk]. One dispatch, blockIdx ranges select the job.
// ---------------------------------------------------------------------------
__global__ __launch_bounds__(256) void prep(
    const float* __restrict__ x,  const float* __restrict__ Wq,
    const float* __restrict__ Wk, const float* __restrict__ Wv,
    const float* __restrict__ Wo, const float* __restrict__ bq,
    const float* __restrict__ bk,
    _Float16* __restrict__ x2,  _Float16* __restrict__ w2q,
    _Float16* __restrict__ w2k, _Float16* __restrict__ wv16,
    _Float16* __restrict__ wo16, float* __restrict__ bqk) {
    const int bid = blockIdx.x;
    if (bid < 5120) {           // split jobs: x / Wq / Wk
        const float* src; _Float16* dst; int t;
        if (bid < 4096)      { src = x;  dst = x2;  t = bid * 256 + threadIdx.x; }
        else if (bid < 4608) { src = Wq; dst = w2q; t = (bid - 4096) * 256 + threadIdx.x; }
        else                 { src = Wk; dst = w2k; t = (bid - 4608) * 256 + threadIdx.x; }
        int m = t >> 7, kc = (t & 127) << 3;
        const float* s = src + (size_t)m * 1024 + kc;
        f32x4 a = *(const f32x4*)s;
        f32x4 b = *(const f32x4*)(s + 4);
        float xs[8] = {a.x, a.y, a.z, a.w, b.x, b.y, b.z, b.w};
        half8 hi, lo;
        #pragma unroll
        for (int u = 0; u < 8; ++u) {
            _Float16 h = (_Float16)xs[u];
            hi[u] = h;
            lo[u] = (_Float16)(xs[u] - (float)h);
        }
        *(half8*)(dst + (size_t)m * 2048 + kc)        = hi;
        *(half8*)(dst + (size_t)m * 2048 + 1024 + kc) = lo;
    } else if (bid < 6144) {    // conv jobs: Wv / Wo
        const float* src; _Float16* dst; int t;
        if (bid < 5632) { src = Wv; dst = wv16; t = (bid - 5120) * 256 + threadIdx.x; }
        else            { src = Wo; dst = wo16; t = (bid - 5632) * 256 + threadIdx.x; }
        int m = t >> 7, kc = (t & 127) << 3;
        const float* s = src + (size_t)m * 1024 + kc;
        f32x4 a = *(const f32x4*)s;
        f32x4 b = *(const f32x4*)(s + 4);
        float xs[8] = {a.x, a.y, a.z, a.w, b.x, b.y, b.z, b.w};
        half8 hv;
        #pragma unroll
        for (int u = 0; u < 8; ++u) hv[u] = (_Float16)xs[u];
        *(half8*)(dst + (size_t)m * 1024 + kc) = hv;
    } else {                    // bias concat
        int i = (bid - 6144) * 256 + threadIdx.x;
        bqk[i] = (i < 1024) ? bq[i] : bk[i - 1024];
    }
}

// ---------------------------------------------------------------------------
// Merged q+k split GEMM. N=2048 (cols 0..1023 -> q, 1024..2047 -> k).
// K=3072 logical ([hi*hi | lo*hi | hi*lo]). silu. Writes fp32 (direct, 64B
// chunks) + f16 (LDS slab transpose -> coalesced half8 stores).
// Grid 64x16 = 1024 blocks -> 4 blocks/CU.
// ---------------------------------------------------------------------------
__global__ __launch_bounds__(256, 4) void gemm_qk(
    const _Float16* __restrict__ A,   // x2, lda 2048
    const _Float16* __restrict__ B,   // [w2q; w2k], ldb 2048
    const float* __restrict__ bqk,
    float* __restrict__ Q32, float* __restrict__ K32,
    _Float16* __restrict__ Q16, _Float16* __restrict__ K16) {
    __shared__ __align__(16) _Float16 sA[4096];
    __shared__ __align__(16) _Float16 sB[4096];
    __shared__ __align__(16) _Float16 sC16[32 * 136];

    const int tid  = threadIdx.x;
    const int lane = tid & 63;
    const int w    = tid >> 6;
    const int row0 = blockIdx.x * 128;
    const int col0 = blockIdx.y * 128;
    const int wm   = (w & 1) * 64;
    const int wn   = (w >> 1) * 64;

    const int ch0 = w * 64 + lane;
    const int rS0 = ch0 >> 2;
    const int cS0 = (ch0 & 3) ^ ((rS0 >> 1) & 3);
    const int ch1 = ch0 + 256;
    const int rS1 = ch1 >> 2;
    const int cS1 = (ch1 & 3) ^ ((rS1 >> 1) & 3);

    f32x4 acc[4][4];
    #pragma unroll
    for (int i = 0; i < 4; ++i)
        #pragma unroll
        for (int j = 0; j < 4; ++j) { f32x4 z = {0.f, 0.f, 0.f, 0.f}; acc[i][j] = z; }

    const int ml = lane & 15;
    const int kg = lane >> 4;
    int offA[4], offB[4];
    #pragma unroll
    for (int i = 0; i < 4; ++i) {
        int r  = wm + i * 16 + ml;
        offA[i] = r * 32 + (kg ^ ((r >> 1) & 3)) * 8;
        int rn = wn + i * 16 + ml;
        offB[i] = rn * 32 + (kg ^ ((rn >> 1) & 3)) * 8;
    }

    for (int kit = 0; kit < 96; ++kit) {
        const int k0   = kit * 32;
        const int acol = (k0 < 2048) ? k0 : k0 - 2048;
        const int bcol = (k0 < 1024) ? k0 : k0 - 1024;

        gld_lds16(A + (size_t)(row0 + rS0) * 2048 + acol + cS0 * 8, &sA[w * 512]);
        gld_lds16(A + (size_t)(row0 + rS1) * 2048 + acol + cS1 * 8, &sA[2048 + w * 512]);
        gld_lds16(B + (size_t)(col0 + rS0) * 2048 + bcol + cS0 * 8, &sB[w * 512]);
        gld_lds16(B + (size_t)(col0 + rS1) * 2048 + bcol + cS1 * 8, &sB[2048 + w * 512]);
        __syncthreads();

        half8 af[4], bf[4];
        #pragma unroll
        for (int i = 0; i < 4; ++i) {
            af[i] = *(const half8*)&sA[offA[i]];
            bf[i] = *(const half8*)&sB[offB[i]];
        }
        #pragma unroll
        for (int i = 0; i < 4; ++i)
            #pragma unroll
            for (int j = 0; j < 4; ++j)
                acc[i][j] = __builtin_amdgcn_mfma_f32_16x16x32_f16(af[i], bf[j], acc[i][j], 0, 0, 0);
        __syncthreads();
    }

    const int colq = (col0 < 1024) ? col0 : col0 - 1024;
    float*    Y32  = (col0 < 1024) ? Q32 : K32;
    _Float16* Y16  = (col0 < 1024) ? Q16 : K16;

    // activation + fp32 direct stores; keep activated values in acc
    const int rg = lane >> 4;
    #pragma unroll
    for (int j = 0; j < 4; ++j) {
        const float bv = bqk[col0 + wn + j * 16 + ml];
        const int nn = colq + wn + j * 16 + ml;
        #pragma unroll
        for (int i = 0; i < 4; ++i) {
            #pragma unroll
            for (int t = 0; t < 4; ++t) {
                float vv = acc[i][j][t] + bv;
                vv = vv / (1.f + expf(-vv));     // silu
                acc[i][j][t] = vv;
                int mm = row0 + wm + i * 16 + rg * 4 + t;
                Y32[(size_t)mm * 1024 + nn] = vv;
            }
        }
    }
    // f16 via LDS slab transpose (4 slabs of 32 rows)
    for (int s = 0; s < 4; ++s) {
        if ((wm == 0) == (s < 2)) {
            const int ib = (s & 1) * 2;
            #pragma unroll
            for (int ii = 0; ii < 2; ++ii)
                #pragma unroll
                for (int j = 0; j < 4; ++j)
                    #pragma unroll
                    for (int t = 0; t < 4; ++t) {
                        int lr = ii * 16 + rg * 4 + t;
                        sC16[lr * 136 + wn + j * 16 + ml] = (_Float16)acc[ib + ii][j][t];
                    }
        }
        __syncthreads();
        #pragma unroll
        for (int u = 0; u < 2; ++u) {
            int c = u * 256 + tid;
            int r = c >> 4, cc = (c & 15) * 8;
            half8 hv = *(const half8*)&sC16[r * 136 + cc];
            *(half8*)(Y16 + (size_t)(row0 + 32 * s + r) * 1024 + colq + cc) = hv;
        }
        __syncthreads();
    }
}

// ---------------------------------------------------------------------------
// Generic f16 MFMA GEMM (v-proj, final). W32: direct fp32; W16: slab-coalesced.
// ---------------------------------------------------------------------------
template<int KITERS, int ACT, int W32, int W16>
__global__ __launch_bounds__(256, 4) void gemm_f16(
    const _Float16* __restrict__ A, int lda,
    const _Float16* __restrict__ B, int ldb,
    const float* __restrict__ bias,
    float* __restrict__ Y32, _Float16* __restrict__ Y16, float outscale) {
    __shared__ __align__(16) _Float16 sA[4096];
    __shared__ __align__(16) _Float16 sB[4096];
    __shared__ __align__(16) _Float16 sC16[32 * 136];

    const int tid  = threadIdx.x;
    const int lane = tid & 63;
    const int w    = tid >> 6;
    const int row0 = blockIdx.x * 128;
    const int col0 = blockIdx.y * 128;
    const int wm   = (w & 1) * 64;
    const int wn   = (w >> 1) * 64;

    const int ch0 = w * 64 + lane;
    const int rS0 = ch0 >> 2;
    const int cS0 = (ch0 & 3) ^ ((rS0 >> 1) & 3);
    const int ch1 = ch0 + 256;
    const int rS1 = ch1 >> 2;
    const int cS1 = (ch1 & 3) ^ ((rS1 >> 1) & 3);

    f32x4 acc[4][4];
    #pragma unroll
    for (int i = 0; i < 4; ++i)
        #pragma unroll
        for (int j = 0; j < 4; ++j) { f32x4 z = {0.f, 0.f, 0.f, 0.f}; acc[i][j] = z; }

    const int ml = lane & 15;
    const int kg = lane >> 4;
    int offA[4], offB[4];
    #pragma unroll
    for (int i = 0; i < 4; ++i) {
        int r  = wm + i * 16 + ml;
        offA[i] = r * 32 + (kg ^ ((r >> 1) & 3)) * 8;
        int rn = wn + i * 16 + ml;
        offB[i] = rn * 32 + (kg ^ ((rn >> 1) & 3)) * 8;
    }

    for (int kit = 0; kit < KITERS; ++kit) {
        const int k0 = kit * 32;
        gld_lds16(A + (size_t)(row0 + rS0) * lda + k0 + cS0 * 8, &sA[w * 512]);
        gld_lds16(A + (size_t)(row0 + rS1) * lda + k0 + cS1 * 8, &sA[2048 + w * 512]);
        gld_lds16(B + (size_t)(col0 + rS0) * ldb + k0 + cS0 * 8, &sB[w * 512]);
        gld_lds16(B + (size_t)(col0 + rS1) * ldb + k0 + cS1 * 8, &sB[2048 + w * 512]);
        __syncthreads();

        half8 af[4], bf[4];
        #pragma unroll
        for (int i = 0; i < 4; ++i) {
            af[i] = *(const half8*)&sA[offA[i]];
            bf[i] = *(const half8*)&sB[offB[i]];
        }
        #pragma unroll
        for (int i = 0; i < 4; ++i)
            #pragma unroll
            for (int j = 0; j < 4; ++j)
                acc[i][j] = __builtin_amdgcn_mfma_f32_16x16x32_f16(af[i], bf[j], acc[i][j], 0, 0, 0);
        __syncthreads();
    }

    const int rg = lane >> 4;
    #pragma unroll
    for (int j = 0; j < 4; ++j) {
        const int nn = col0 + wn + j * 16 + ml;
        const float bv = bias[nn];
        #pragma unroll
        for (int i = 0; i < 4; ++i) {
            #pragma unroll
            for (int t = 0; t < 4; ++t) {
                float vv = acc[i][j][t] * outscale + bv;
                if (ACT) vv = vv / (1.f + expf(-vv));
                acc[i][j][t] = vv;
                if (W32) {
                    int mm = row0 + wm + i * 16 + rg * 4 + t;
                    Y32[(size_t)mm * 1024 + nn] = vv;
                }
            }
        }
    }
    if (W16) {
        for (int s = 0; s < 4; ++s) {
            if ((wm == 0) == (s < 2)) {
                const int ib = (s & 1) * 2;
                #pragma unroll
                for (int ii = 0; ii < 2; ++ii)
                    #pragma unroll
                    for (int j = 0; j < 4; ++j)
                        #pragma unroll
                        for (int t = 0; t < 4; ++t) {
                            int lr = ii * 16 + rg * 4 + t;
                            sC16[lr * 136 + wn + j * 16 + ml] = (_Float16)acc[ib + ii][j][t];
                        }
            }
            __syncthreads();
            #pragma unroll
            for (int u = 0; u < 2; ++u) {
                int c = u * 256 + tid;
                int r = c >> 4, cc = (c & 15) * 8;
                half8 hv = *(const half8*)&sC16[r * 136 + cc];
                *(half8*)(Y16 + (size_t)(row0 + 32 * s + r) * 1024 + col0 + cc) = hv;
            }
            __syncthreads();
        }
    }
}

// ---------------------------------------------------------------------------
// chunk stats: kvT[blk][e][f] = sum_j v16[j][e]*k16[j][f] via MFMA;
// ksum[blk][f] fp32 from kf32 (precision-critical, feeds z -> den).
// ---------------------------------------------------------------------------
__global__ __launch_bounds__(256) void chunk_stats(
    const _Float16* __restrict__ k16g, const _Float16* __restrict__ v16g,
    const float* __restrict__ kf32,
    float* __restrict__ kvT, float* __restrict__ ksum) {
    const int blk = blockIdx.x;
    const int n = blk & 15, bh = blk >> 4, h = bh & 15, b = bh >> 4;
    const size_t base = ((size_t)b * L_SEQ + (size_t)n * CHUNK) * D_MODEL + (size_t)h * HDIM;

    __shared__ __align__(16) _Float16 sv[64 * 136];
    __shared__ __align__(16) _Float16 sk[64 * 136];
    __shared__ float sred[4 * 64];

    const int tid = threadIdx.x;
    #pragma unroll
    for (int p = 0; p < 4; ++p) {
        int idx = p * 256 + tid;
        int j = idx >> 3, c = idx & 7;
        half8 vv = *(const half8*)(v16g + base + (size_t)j * D_MODEL + c * 8);
        half8 kk = *(const half8*)(k16g + base + (size_t)j * D_MODEL + c * 8);
        #pragma unroll
        for (int u = 0; u < 8; ++u) {
            sv[(c * 8 + u) * 136 + j] = vv[u];
            sk[(c * 8 + u) * 136 + j] = kk[u];
        }
    }
    __syncthreads();

    const int lane = tid & 63;
    const int w    = tid >> 6;
    const int ml   = lane & 15;
    const int kg   = lane >> 4;

    f32x4 acc[4];
    #pragma unroll
    for (int ft = 0; ft < 4; ++ft) { f32x4 z = {0.f,0.f,0.f,0.f}; acc[ft] = z; }
    #pragma unroll
    for (int ft = 0; ft < 4; ++ft)
        #pragma unroll
        for (int kit = 0; kit < 4; ++kit) {
            half8 af = *(const half8*)&sv[(w * 16 + ml) * 136 + kit * 32 + kg * 8];
            half8 bf = *(const half8*)&sk[(ft * 16 + ml) * 136 + kit * 32 + kg * 8];
            acc[ft] = __builtin_amdgcn_mfma_f32_16x16x32_f16(af, bf, acc[ft], 0, 0, 0);
        }
    float* o = kvT + (size_t)blk * 4096;
    #pragma unroll
    for (int ft = 0; ft < 4; ++ft)
        #pragma unroll
        for (int t = 0; t < 4; ++t) {
            int e = w * 16 + kg * 4 + t;
            o[e * 64 + ft * 16 + ml] = acc[ft][t];
        }

    float s = 0.f;
    for (int j = w * 32; j < w * 32 + 32; ++j)
        s += kf32[base + (size_t)j * D_MODEL + lane];
    sred[w * 64 + lane] = s;
    __syncthreads();
    if (tid < 64)
        ksum[(size_t)blk * 64 + tid] = sred[tid] + sred[64 + tid] + sred[128 + tid] + sred[192 + tid];
}

// ---------------------------------------------------------------------------
// Exclusive cumsum over chunk axis. 1024 blocks: bh = blk>>4, seg = blk&15.
// ---------------------------------------------------------------------------
__global__ __launch_bounds__(256) void scan_chunks(float* __restrict__ kvT,
                                                   float* __restrict__ ksum) {
    const int bh  = blockIdx.x >> 4;
    const int seg = blockIdx.x & 15;
    const int idx = seg * 256 + threadIdx.x;
    float* base = kvT + (size_t)bh * NCHUNK * 4096 + idx;
    float run = 0.f;
    #pragma unroll
    for (int nn = 0; nn < NCHUNK; ++nn) {
        float t = base[(size_t)nn * 4096];
        base[(size_t)nn * 4096] = run;
        run += t;
    }
    if (seg == 0 && threadIdx.x < 64) {
        float* zb = ksum + (size_t)bh * NCHUNK * 64 + threadIdx.x;
        float r2 = 0.f;
        #pragma unroll
        for (int nn = 0; nn < NCHUNK; ++nn) {
            float t = zb[nn * 64];
            zb[nn * 64] = r2;
            r2 += t;
        }
    }
}

// ---------------------------------------------------------------------------
// den[b,h,l] = q_l . (cumsum_{j<=l} k_j)  — all fp32 (precision-critical).
// ---------------------------------------------------------------------------
__global__ __launch_bounds__(256) void den_kernel(
    const float* __restrict__ qf32, const float* __restrict__ kf32,
    const float* __restrict__ zg, float* __restrict__ deng) {
    const int blk = blockIdx.x;
    const int n = blk & 15, bh = blk >> 4, h = bh & 15, b = bh >> 4;
    const size_t base = ((size_t)b * L_SEQ + (size_t)n * CHUNK) * D_MODEL + (size_t)h * HDIM;

    __shared__ float skk[128 * 64];
    __shared__ float part[4 * 64];

    const int tid = threadIdx.x;
    #pragma unroll
    for (int p = 0; p < 8; ++p) {
        int idx = p * 256 + tid;
        int j = idx >> 4, fc = (idx & 15) * 4;
        *(f32x4*)&skk[j * 64 + fc] = *(const f32x4*)(kf32 + base + (size_t)j * D_MODEL + fc);
    }
    __syncthreads();

    const int w = tid >> 6, lane = tid & 63;
    float ps = 0.f;
    for (int j = w * 32; j < w * 32 + 32; ++j) ps += skk[j * 64 + lane];
    part[w * 64 + lane] = ps;
    __syncthreads();

    float acc = zg[(size_t)blk * 64 + lane];
    for (int w2 = 0; w2 < w; ++w2) acc += part[w2 * 64 + lane];

    float* dout = deng + ((size_t)(b * 16 + h)) * L_SEQ + n * CHUNK;
    for (int jj = 0; jj < 32; ++jj) {
        int j = w * 32 + jj;
        acc += skk[j * 64 + lane];
        float d = qf32[base + (size_t)j * D_MODEL + lane] * acc;
        #pragma unroll
        for (int off = 32; off > 0; off >>= 1) d += __shfl_xor(d, off, 64);
        if (lane == 0) dout[j] = d;
    }
}

// ---------------------------------------------------------------------------
// MFMA attention core (unchanged from R3).
// ---------------------------------------------------------------------------
__global__ __launch_bounds__(256) void attn_core(
    const _Float16* __restrict__ q16g, const _Float16* __restrict__ k16g,
    const _Float16* __restrict__ v16g, const float* __restrict__ STg,
    const float* __restrict__ deng, _Float16* __restrict__ O16) {
    const int blk = blockIdx.x;
    const int n = blk & 15, bh = blk >> 4, h = bh & 15, b = bh >> 4;
    const size_t base = ((size_t)b * L_SEQ + (size_t)n * CHUNK) * D_MODEL + (size_t)h * HDIM;

    __shared__ __align__(16) _Float16 sq [128 * 72];
    __shared__ __align__(16) _Float16 sk [128 * 72];
    __shared__ __align__(16) _Float16 sv [64 * 136];
    __shared__ __align__(16) _Float16 sS [64 * 72];
    __shared__ __align__(16) _Float16 ssc[64 * 136];
    __shared__ float sden[128];

    const int tid = threadIdx.x;
    #pragma unroll
    for (int p = 0; p < 4; ++p) {
        int idx = p * 256 + tid;
        int j = idx >> 3, c = idx & 7;
        *(half8*)&sq[j * 72 + c * 8] = *(const half8*)(q16g + base + (size_t)j * D_MODEL + c * 8);
        *(half8*)&sk[j * 72 + c * 8] = *(const half8*)(k16g + base + (size_t)j * D_MODEL + c * 8);
        half8 vv = *(const half8*)(v16g + base + (size_t)j * D_MODEL + c * 8);
        #pragma unroll
        for (int u = 0; u < 8; ++u) sv[(c * 8 + u) * 136 + j] = vv[u];
    }
    #pragma unroll
    for (int p = 0; p < 2; ++p) {
        int idx = p * 256 + tid;
        int e = idx >> 3, c = idx & 7;
        f32x4 a = *(const f32x4*)(STg + (size_t)blk * 4096 + e * 64 + c * 8);
        f32x4 b4 = *(const f32x4*)(STg + (size_t)blk * 4096 + e * 64 + c * 8 + 4);
        half8 hv;
        hv[0] = (_Float16)a.x;  hv[1] = (_Float16)a.y;
        hv[2] = (_Float16)a.z;  hv[3] = (_Float16)a.w;
        hv[4] = (_Float16)b4.x; hv[5] = (_Float16)b4.y;
        hv[6] = (_Float16)b4.z; hv[7] = (_Float16)b4.w;
        *(half8*)&sS[e * 72 + c * 8] = hv;
    }
    if (tid < 128) sden[tid] = deng[((size_t)(b * 16 + h)) * L_SEQ + n * CHUNK + tid];
    __syncthreads();

    const int lane = tid & 63;
    const int w    = tid >> 6;
    const int ml   = lane & 15;
    const int kg   = lane >> 4;

    for (int h2 = 0; h2 < 2; ++h2) {
        const int r0 = h2 * 64 + w * 16;
        const int rowmax = r0 + 15;

        f32x4 acc1[8];
        #pragma unroll
        for (int nt = 0; nt < 8; ++nt) { f32x4 z = {0.f,0.f,0.f,0.f}; acc1[nt] = z; }
        #pragma unroll
        for (int nt = 0; nt < 8; ++nt) {
            if (nt * 16 <= rowmax) {
                #pragma unroll
                for (int kit = 0; kit < 2; ++kit) {
                    half8 af = *(const half8*)&sq[(r0 + ml) * 72 + kit * 32 + kg * 8];
                    half8 bf = *(const half8*)&sk[(nt * 16 + ml) * 72 + kit * 32 + kg * 8];
                    acc1[nt] = __builtin_amdgcn_mfma_f32_16x16x32_f16(af, bf, acc1[nt], 0, 0, 0);
                }
            }
        }
        #pragma unroll
        for (int nt = 0; nt < 8; ++nt) {
            #pragma unroll
            for (int t = 0; t < 4; ++t) {
                int lr = w * 16 + kg * 4 + t;
                int ig = h2 * 64 + lr;
                int jg = nt * 16 + ml;
                float val = (jg <= ig) ? acc1[nt][t] : 0.f;
                ssc[lr * 136 + jg] = (_Float16)val;
            }
        }
        __syncthreads();

        f32x4 acc2[4];
        #pragma unroll
        for (int et = 0; et < 4; ++et) { f32x4 z = {0.f,0.f,0.f,0.f}; acc2[et] = z; }
        const int nkit = (h2 == 0) ? 2 : 4;
        #pragma unroll
        for (int et = 0; et < 4; ++et) {
            for (int kit = 0; kit < nkit; ++kit) {
                half8 af = *(const half8*)&ssc[(w * 16 + ml) * 136 + kit * 32 + kg * 8];
                half8 bf = *(const half8*)&sv[(et * 16 + ml) * 136 + kit * 32 + kg * 8];
                acc2[et] = __builtin_amdgcn_mfma_f32_16x16x32_f16(af, bf, acc2[et], 0, 0, 0);
            }
            #pragma unroll
            for (int kit = 0; kit < 2; ++kit) {
                half8 af = *(const half8*)&sq[(r0 + ml) * 72 + kit * 32 + kg * 8];
                half8 bf = *(const half8*)&sS[(et * 16 + ml) * 72 + kit * 32 + kg * 8];
                acc2[et] = __builtin_amdgcn_mfma_f32_16x16x32_f16(af, bf, acc2[et], 0, 0, 0);
            }
        }
        #pragma unroll
        for (int t = 0; t < 4; ++t) {
            int lr = w * 16 + kg * 4 + t;
            int ig = h2 * 64 + lr;
            float rc = 0.015625f / fmaxf(sden[ig], EPS_DEN);
            #pragma unroll
            for (int et = 0; et < 4; ++et) {
                int e = et * 16 + ml;
                O16[base + (size_t)ig * D_MODEL + e] = (_Float16)(acc2[et][t] * rc);
            }
        }
        __syncthreads();
    }
}

// ---------------------------------------------------------------------------
extern "C" void kernel_launch(void* const* d_in, const int* in_sizes, int n_in,
                              void* d_out, int out_size, void* d_ws, size_t ws_size,
                              hipStream_t stream) {
    const float* x  = (const float*)d_in[0];
    const float* Wq = (const float*)d_in[1];
    const float* bq = (const float*)d_in[2];
    const float* Wk = (const float*)d_in[3];
    const float* bk = (const float*)d_in[4];
    const float* Wv = (const float*)d_in[5];
    const float* bv = (const float*)d_in[6];
    const float* Wo = (const float*)d_in[7];
    const float* bo = (const float*)d_in[8];
    float* out = (float*)d_out;

    char* p = (char*)d_ws;
    _Float16* x2   = (_Float16*)p;  p += (size_t)NTOK * 2048 * 2;
    _Float16* w2q  = (_Float16*)p;  p += (size_t)1024 * 2048 * 2;
    _Float16* w2k  = (_Float16*)p;  p += (size_t)1024 * 2048 * 2;   // contiguous after w2q
    _Float16* wv16 = (_Float16*)p;  p += (size_t)1024 * 1024 * 2;
    _Float16* wo16 = (_Float16*)p;  p += (size_t)1024 * 1024 * 2;
    float* qf   = (float*)p;        p += (size_t)NTOK * 1024 * 4;
    float* kf   = (float*)p;        p += (size_t)NTOK * 1024 * 4;
    _Float16* q16 = (_Float16*)p;   p += (size_t)NTOK * 1024 * 2;
    _Float16* k16 = (_Float16*)p;   p += (size_t)NTOK * 1024 * 2;
    _Float16* v16 = (_Float16*)p;   p += (size_t)NTOK * 1024 * 2;
    float* kvT  = (float*)p;        p += (size_t)1024 * 4096 * 4;
    float* ksb  = (float*)p;        p += (size_t)1024 * 64 * 4;
    float* den  = (float*)p;        p += (size_t)B_SZ * HEADS * L_SEQ * 4;
    float* bqk  = (float*)p;        p += 2048 * 4;
    _Float16* attn16 = x2;  // x2 dead after the two projection GEMMs

    prep<<<6152, 256, 0, stream>>>(x, Wq, Wk, Wv, Wo, bq, bk,
                                   x2, w2q, w2k, wv16, wo16, bqk);

    gemm_qk<<<dim3(64, 16), 256, 0, stream>>>(x2, w2q, bqk, qf, kf, q16, k16);
    gemm_f16<32, 0, 0, 1><<<dim3(64, 8), 256, 0, stream>>>(x2, 2048, wv16, 1024, bv,
                                                           nullptr, v16, 1.f);

    chunk_stats<<<1024, 256, 0, stream>>>(k16, v16, kf, kvT, ksb);
    scan_chunks<<<1024, 256, 0, stream>>>(kvT, ksb);
    den_kernel<<<1024, 256, 0, stream>>>(qf, kf, ksb, den);
    attn_core<<<1024, 256, 0, stream>>>(q16, k16, v16, kvT, den, attn16);

    gemm_f16<32, 0, 1, 0><<<dim3(64, 8), 256, 0, stream>>>(attn16, 1024, wo16, 1024, bo,
                                                           out, nullptr, 64.f);
}